// Round 6
// baseline (2684.361 us; speedup 1.0000x reference)
//
#include <hip/hip_runtime.h>
#include <cmath>

// Problem constants
#define CN   256   // channels (N_DIST)
#define HN   256   // H
#define WN   192   // W
#define KN   129   // kernel taps
#define RN   64    // radius
#define SN   256   // padded size
#define PADN 32    // (SN - WN)/2

// ================= conv along W (last axis), 4-stage LDS =================
// Block: 256 thr = 4 waves. Tile: 64 rows x 64 output cols; lane = row.
// Taps in 4 stages of 32 (+1); stage slab = 64 x 96 window cols in LDS
// (pitch 97, odd => lane-strided b32 conflict-free; 25.4 KB).
// Inner loop: groups of 16 taps on three 16-reg half-buffers; the 16
// ds_reads of half g+2 are issued ~512 issue-cycles before consumption.
// Coefficients in LDS, float4 one 4-tap block ahead.
template <int WD, bool ACC>
__global__ __launch_bounds__(256, 5) void conv_w_lds(const float* __restrict__ in,
                                                     const float* __restrict__ kern,
                                                     float* __restrict__ out) {
    constexpr int PITCH = 97;
    __shared__ float lds[64 * PITCH + 132];
    float* __restrict__ ldsK = lds + 64 * PITCH;
    const int tid = threadIdx.x;
    const int x0  = blockIdx.x * 64;
    const int h0  = blockIdx.y * 64;
    const int c   = blockIdx.z;
    const float* __restrict__ in_c = in + ((size_t)c * HN + h0) * WD;

    if (tid < 132) ldsK[tid] = (tid < KN) ? kern[c * KN + tid] : 0.f;

    const int wv = tid >> 6;            // wave -> output col chunk
    const int l  = tid & 63;            // lane = row
    const int base  = l * PITCH + wv * 16;
    const int col32 = tid & 31;         // staging decomposition
    const int r8    = tid >> 5;         // 0..7

    float acc[16];
#pragma unroll
    for (int t = 0; t < 16; ++t) acc[t] = 0.f;

#pragma unroll 1
    for (int s = 0; s < 4; ++s) {
        __syncthreads();                // prior stage reads done
        const int off = x0 + 32 * s - 64;   // global col of slab col 0
        if (off >= 0 && off + 96 <= WD) {   // interior: no bounds code
#pragma unroll
            for (int m = 0; m < 3; ++m)
#pragma unroll
                for (int k = 0; k < 8; ++k)
                    lds[(r8 + 8 * k) * PITCH + col32 + 32 * m] =
                        in_c[(size_t)(r8 + 8 * k) * WD + off + col32 + 32 * m];
        } else {
#pragma unroll
            for (int m = 0; m < 3; ++m)
#pragma unroll
                for (int k = 0; k < 8; ++k) {
                    int g  = off + col32 + 32 * m;
                    int gc = min(max(g, 0), WD - 1);
                    float v = in_c[(size_t)(r8 + 8 * k) * WD + gc];
                    lds[(r8 + 8 * k) * PITCH + col32 + 32 * m] = (g == gc) ? v : 0.f;
                }
        }
        __syncthreads();

        float H0[16], H1[16], H2[16];
#pragma unroll
        for (int i = 0; i < 16; ++i) H0[i] = lds[base + i];
#pragma unroll
        for (int i = 0; i < 16; ++i) H1[i] = lds[base + 16 + i];

        const float4* __restrict__ k4 = (const float4*)ldsK;
        float4 kc = k4[8 * s];
#pragma unroll
        for (int q = 0; q < 8; ++q) {       // 4 taps per q, 32 taps/stage
            float4 kn = (q < 7) ? k4[8 * s + q + 1] : kc;
#pragma unroll
            for (int u = 0; u < 4; ++u) {
                const int up = 4 * q + u;
                const float kj = (u == 0) ? kc.x : (u == 1) ? kc.y
                               : (u == 2) ? kc.z : kc.w;
#pragma unroll
                for (int t = 0; t < 16; ++t) {
                    const int e = up + t;   // compile-time after unroll
                    const float val = (e < 16) ? H0[e]
                                    : (e < 32) ? H1[e - 16] : H2[e - 32];
                    acc[t] = fmaf(val, kj, acc[t]);
                }
            }
            if (q == 0) {                   // prefetch H2: consumed from q=4
#pragma unroll
                for (int i = 0; i < 16; ++i) H2[i] = lds[base + 32 + i];
            }
            kc = kn;
        }
        if (s == 3) {                       // tap 128 uses H2 exactly
            const float k128 = ldsK[128];
#pragma unroll
            for (int t = 0; t < 16; ++t) acc[t] = fmaf(H2[t], k128, acc[t]);
        }
    }

    float4* __restrict__ o4 =
        (float4*)(out + ((size_t)c * HN + h0 + l) * WD + x0 + wv * 16);
#pragma unroll
    for (int q = 0; q < 4; ++q) {
        float4 v;
        v.x = acc[4*q]; v.y = acc[4*q+1]; v.z = acc[4*q+2]; v.w = acc[4*q+3];
        if (ACC) {
            float4 o = o4[q];
            v.x += o.x; v.y += o.y; v.z += o.z; v.w += o.w;
        }
        o4[q] = v;
    }
}

// ================= conv along H (axis 1), direct-global =================
// Lane = col => window loads are 64-lane coalesced global reads; no LDS,
// no barriers. 3 rotating 16-reg halves, prefetch one full group (~512
// issue-cycles) ahead. Coefficients via wave-uniform s_load (no DS ops
// in kernel, so no lgkm mixing).
__global__ __launch_bounds__(256, 5) void conv_h_glb(const float* __restrict__ in,
                                                     const float* __restrict__ kern,
                                                     float* __restrict__ out) {
    const int tid = threadIdx.x;
    const int x0  = blockIdx.x * 64;
    const int h0  = blockIdx.y * 64;
    const int c   = blockIdx.z;
    const int wv  = tid >> 6;           // wave -> output row chunk
    const int l   = tid & 63;           // lane = col
    const float* __restrict__ colp = in + (size_t)c * HN * WN + x0 + l;
    const float* __restrict__ krow = kern + c * KN;   // uniform -> s_load
    const int r0 = h0 + wv * 16 - 64;   // global row of window element 0

    float H[3][16], acc[16];
#pragma unroll
    for (int t = 0; t < 16; ++t) acc[t] = 0.f;

    auto loadrow = [&](int e) -> float {
        int r  = r0 + e;                       // wave-uniform
        int rc = min(max(r, 0), HN - 1);
        float v = colp[(size_t)rc * WN];
        return (r == rc) ? v : 0.f;
    };

#pragma unroll
    for (int i = 0; i < 16; ++i) H[0][i] = loadrow(i);
#pragma unroll
    for (int i = 0; i < 16; ++i) H[1][i] = loadrow(16 + i);

#pragma unroll
    for (int g = 0; g < 8; ++g) {
        if (g < 7) {                    // prefetch half g+2 (phys (g+2)%3)
#pragma unroll
            for (int i = 0; i < 16; ++i)
                H[(g + 2) % 3][i] = loadrow(16 * (g + 2) + i);
        }
#pragma unroll
        for (int u = 0; u < 16; ++u) {
            const float kj = krow[16 * g + u];
#pragma unroll
            for (int t = 0; t < 16; ++t) {
                const int e  = 16 * g + u + t;       // in [16g, 16g+30]
                const int hh = (e >> 4) % 3, ii = e & 15;
                acc[t] = fmaf(H[hh][ii], kj, acc[t]);
            }
        }
    }
    {   // tap 128: elements 128..143 = half 8 -> phys 2
        const float k128 = krow[128];
#pragma unroll
        for (int t = 0; t < 16; ++t) acc[t] = fmaf(H[2][t], k128, acc[t]);
    }

    float* __restrict__ ob = out + ((size_t)c * HN + h0 + wv * 16) * WN + x0 + l;
#pragma unroll
    for (int t = 0; t < 16; ++t) ob[(size_t)t * WN] = acc[t];
}

// ---------------- forward rotate of implicitly-padded C ----------------
// Branchless: clamped in-bounds addresses + zero weights; 4 outputs/thread.
__global__ __launch_bounds__(256) void rot_fwd_k(const float* __restrict__ Cin,
                                                 float* __restrict__ out,
                                                 float ca, float sa) {
    const int jb = blockIdx.x * 128 + threadIdx.x;  // + q*32
    const int i  = blockIdx.y * 8 + threadIdx.y;    // 0..255
    const int c  = blockIdx.z;
    const float cc = (SN - 1) * 0.5f;               // 127.5
    const float yy = (float)i - cc;
    const float* __restrict__ base = Cin + (size_t)c * HN * WN;
    float* __restrict__ orow = out + ((size_t)c * SN + i) * SN;
#pragma unroll
    for (int q = 0; q < 4; ++q) {
        const int j = jb + q * 32;
        float xx = (float)j - cc;
        float sy = ca * yy + sa * xx + cc;
        float sx = -sa * yy + ca * xx + cc;
        float y0f = floorf(sy), x0f = floorf(sx);
        float fy = sy - y0f, fx = sx - x0f;
        int y0 = (int)y0f, x0i = (int)x0f;
        int p  = x0i - PADN;                        // col into C
        int y0c = min(max(y0, 0), HN - 1);
        int y1c = min(max(y0 + 1, 0), HN - 1);
        int p0c = min(max(p, 0), WN - 1);
        int p1c = min(max(p + 1, 0), WN - 1);
        float wy0 = ((unsigned)y0       < (unsigned)HN) ? (1.f - fy) : 0.f;
        float wy1 = ((unsigned)(y0 + 1) < (unsigned)HN) ? fy : 0.f;
        float wx0 = ((unsigned)p        < (unsigned)WN) ? (1.f - fx) : 0.f;
        float wx1 = ((unsigned)(p + 1)  < (unsigned)WN) ? fx : 0.f;
        const float* r0 = base + (size_t)y0c * WN;
        const float* r1 = base + (size_t)y1c * WN;
        float v00 = r0[p0c], v01 = r0[p1c];
        float v10 = r1[p0c], v11 = r1[p1c];
        orow[j] = wy0 * (wx0 * v00 + wx1 * v01) + wy1 * (wx0 * v10 + wx1 * v11);
    }
}

// ---------------- inverse rotate + accumulate into cropped acc -------------
__global__ __launch_bounds__(256) void rot_bwd_k(const float* __restrict__ U,
                                                 float* __restrict__ acc,
                                                 float ca, float sa) {
    const int xb = blockIdx.x * 64 + threadIdx.x;  // + q*32
    const int i  = blockIdx.y * 8 + threadIdx.y;   // 0..255
    const int c  = blockIdx.z;
    const float cc = (SN - 1) * 0.5f;
    const float yy = (float)i - cc;
    const float* __restrict__ base = U + (size_t)c * SN * SN;
    float* __restrict__ arow = acc + ((size_t)c * HN + i) * WN;
#pragma unroll
    for (int q = 0; q < 2; ++q) {
        const int xc = xb + q * 32;
        const int j  = xc + PADN;
        float xx = (float)j - cc;
        float sy = ca * yy + sa * xx + cc;
        float sx = -sa * yy + ca * xx + cc;
        float y0f = floorf(sy), x0f = floorf(sx);
        float fy = sy - y0f, fx = sx - x0f;
        int y0 = (int)y0f, x0i = (int)x0f;
        int y0c = min(max(y0, 0), SN - 1);
        int y1c = min(max(y0 + 1, 0), SN - 1);
        int p0c = min(max(x0i, 0), SN - 1);
        int p1c = min(max(x0i + 1, 0), SN - 1);
        float wy0 = ((unsigned)y0        < (unsigned)SN) ? (1.f - fy) : 0.f;
        float wy1 = ((unsigned)(y0 + 1)  < (unsigned)SN) ? fy : 0.f;
        float wx0 = ((unsigned)x0i       < (unsigned)SN) ? (1.f - fx) : 0.f;
        float wx1 = ((unsigned)(x0i + 1) < (unsigned)SN) ? fx : 0.f;
        const float* r0 = base + (size_t)y0c * SN;
        const float* r1 = base + (size_t)y1c * SN;
        float v00 = r0[p0c], v01 = r0[p1c];
        float v10 = r1[p0c], v11 = r1[p1c];
        arow[xc] += wy0 * (wx0 * v00 + wx1 * v01) + wy1 * (wx0 * v10 + wx1 * v11);
    }
}

// ---------------- finalize: out = (C + acc) / norm[c], float4 ----------------
__global__ __launch_bounds__(256) void final_k(float* __restrict__ outC,
                                               const float* __restrict__ acc,
                                               const float* __restrict__ norm) {
    size_t i4 = (size_t)blockIdx.x * 256 + threadIdx.x;
    int c = (int)(i4 / (HN * WN / 4));
    float4* o4 = (float4*)outC;
    const float4* a4 = (const float4*)acc;
    float inv = 1.f / norm[c];
    float4 o = o4[i4], a = a4[i4];
    o.x = (o.x + a.x) * inv; o.y = (o.y + a.y) * inv;
    o.z = (o.z + a.z) * inv; o.w = (o.w + a.w) * inv;
    o4[i4] = o;
}

extern "C" void kernel_launch(void* const* d_in, const int* in_sizes, int n_in,
                              void* d_out, int out_size, void* d_ws, size_t ws_size,
                              hipStream_t stream) {
    const float* x    = (const float*)d_in[0];
    const float* kg   = (const float*)d_in[1];
    const float* kw   = (const float*)d_in[2];
    const float* kiso = (const float*)d_in[3];
    const float* norm = (const float*)d_in[4];

    float* C = (float*)d_out;                 // 256*256*192 floats
    float* ws = (float*)d_ws;
    const size_t IMG = (size_t)CN * HN * WN;  // 12,582,912
    const size_t PSQ = (size_t)CN * SN * SN;  // 16,777,216
    float* B   = ws;                          // IMG
    float* acc = ws + IMG;                    // IMG
    float* T   = ws + 2 * IMG;                // PSQ
    float* U   = T + PSQ;                     // PSQ

    const dim3 blk256(256);
    const dim3 convHGrid(WN / 64, HN / 64, CN);
    const dim3 convW192Grid(WN / 64, HN / 64, CN);
    const dim3 convW256Grid(SN / 64, HN / 64, CN);
    const dim3 rotFGrid(SN / 128, SN / 8, CN), rotBlk(32, 8);
    const dim3 rotBGrid(WN / 64, SN / 8, CN);

    // 1-2: gaussian separable conv -> C (d_out)
    conv_h_glb<<<convHGrid, blk256, 0, stream>>>(x, kg, B);
    conv_w_lds<WN, false><<<convW192Grid, blk256, 0, stream>>>(B, kg, C);
    // 3-4: iso separable conv -> acc
    conv_h_glb<<<convHGrid, blk256, 0, stream>>>(C, kiso, B);
    conv_w_lds<WN, false><<<convW192Grid, blk256, 0, stream>>>(B, kiso, acc);
    // 5: i=0 tail term (identity rotation): acc += conv_w(C, kw)
    conv_w_lds<WN, true><<<convW192Grid, blk256, 0, stream>>>(C, kw, acc);
    // 6-11: i=1,2 tail terms
    const double a1 = 60.0 * M_PI / 180.0, a2 = 120.0 * M_PI / 180.0;
    const float c1 = (float)cos(a1), s1 = (float)sin(a1);
    const float c2 = (float)cos(a2), s2 = (float)sin(a2);

    rot_fwd_k<<<rotFGrid, rotBlk, 0, stream>>>(C, T, c1, s1);
    conv_w_lds<SN, false><<<convW256Grid, blk256, 0, stream>>>(T, kw, U);
    rot_bwd_k<<<rotBGrid, rotBlk, 0, stream>>>(U, acc, c1, -s1);

    rot_fwd_k<<<rotFGrid, rotBlk, 0, stream>>>(C, T, c2, s2);
    conv_w_lds<SN, false><<<convW256Grid, blk256, 0, stream>>>(T, kw, U);
    rot_bwd_k<<<rotBGrid, rotBlk, 0, stream>>>(U, acc, c2, -s2);

    // 12: out = (C + acc) / norm[c]
    final_k<<<(unsigned)(IMG / 4 / 256), blk256, 0, stream>>>(C, acc, norm);
    (void)in_sizes; (void)n_in; (void)out_size; (void)ws_size;
}

// Round 7
// 817.242 us; speedup vs baseline: 3.2847x; 3.2847x over previous
//
#include <hip/hip_runtime.h>
#include <cmath>

// Problem constants
#define CN   256   // channels (N_DIST)
#define HN   256   // H
#define WN   192   // W
#define KN   129   // kernel taps
#define RN   64    // radius
#define SN   256   // padded size
#define PADN 32    // (SN - WN)/2

// ================= conv along W (last axis), 4-stage LDS =================
// Block: 256 thr = 4 waves. Tile: 64 rows x 64 output cols; lane = row.
// Taps in 4 stages of 32 (+1); stage slab = 64 x 96 window cols in LDS
// (pitch 97, odd => lane-strided b32 conflict-free; 25.4 KB).
// Inner loop: groups of 4 taps on three 16-reg half-buffers; H2's 16
// ds_reads issue ~3 q-blocks (~380 issue-cycles) before first use.
template <int WD, bool ACC>
__global__ __launch_bounds__(256, 5) void conv_w_lds(const float* __restrict__ in,
                                                     const float* __restrict__ kern,
                                                     float* __restrict__ out) {
    constexpr int PITCH = 97;
    __shared__ float lds[64 * PITCH + 132];
    float* __restrict__ ldsK = lds + 64 * PITCH;
    const int tid = threadIdx.x;
    const int x0  = blockIdx.x * 64;
    const int h0  = blockIdx.y * 64;
    const int c   = blockIdx.z;
    const float* __restrict__ in_c = in + ((size_t)c * HN + h0) * WD;

    if (tid < 132) ldsK[tid] = (tid < KN) ? kern[c * KN + tid] : 0.f;

    const int wv = tid >> 6;            // wave -> output col chunk
    const int l  = tid & 63;            // lane = row
    const int base  = l * PITCH + wv * 16;
    const int col32 = tid & 31;         // staging decomposition
    const int r8    = tid >> 5;         // 0..7

    float acc[16];
#pragma unroll
    for (int t = 0; t < 16; ++t) acc[t] = 0.f;

#pragma unroll 1
    for (int s = 0; s < 4; ++s) {
        __syncthreads();                // prior stage reads done
        const int off = x0 + 32 * s - 64;   // global col of slab col 0
        if (off >= 0 && off + 96 <= WD) {   // interior: no bounds code
#pragma unroll
            for (int m = 0; m < 3; ++m)
#pragma unroll
                for (int k = 0; k < 8; ++k)
                    lds[(r8 + 8 * k) * PITCH + col32 + 32 * m] =
                        in_c[(size_t)(r8 + 8 * k) * WD + off + col32 + 32 * m];
        } else {
#pragma unroll
            for (int m = 0; m < 3; ++m)
#pragma unroll
                for (int k = 0; k < 8; ++k) {
                    int g  = off + col32 + 32 * m;
                    int gc = min(max(g, 0), WD - 1);
                    float v = in_c[(size_t)(r8 + 8 * k) * WD + gc];
                    lds[(r8 + 8 * k) * PITCH + col32 + 32 * m] = (g == gc) ? v : 0.f;
                }
        }
        __syncthreads();

        float H0[16], H1[16], H2[16];
#pragma unroll
        for (int i = 0; i < 16; ++i) H0[i] = lds[base + i];
#pragma unroll
        for (int i = 0; i < 16; ++i) H1[i] = lds[base + 16 + i];

        const float4* __restrict__ k4 = (const float4*)ldsK;
        float4 kc = k4[8 * s];
#pragma unroll
        for (int q = 0; q < 8; ++q) {       // 4 taps per q, 32 taps/stage
            float4 kn = (q < 7) ? k4[8 * s + q + 1] : kc;
#pragma unroll
            for (int u = 0; u < 4; ++u) {
                const int up = 4 * q + u;
                const float kj = (u == 0) ? kc.x : (u == 1) ? kc.y
                               : (u == 2) ? kc.z : kc.w;
#pragma unroll
                for (int t = 0; t < 16; ++t) {
                    const int e = up + t;   // compile-time after unroll
                    const float val = (e < 16) ? H0[e]
                                    : (e < 32) ? H1[e - 16] : H2[e - 32];
                    acc[t] = fmaf(val, kj, acc[t]);
                }
            }
            if (q == 0) {                   // prefetch H2: consumed from q=4
#pragma unroll
                for (int i = 0; i < 16; ++i) H2[i] = lds[base + 32 + i];
            }
            kc = kn;
        }
        if (s == 3) {                       // tap 128 uses H2 exactly
            const float k128 = ldsK[128];
#pragma unroll
            for (int t = 0; t < 16; ++t) acc[t] = fmaf(H2[t], k128, acc[t]);
        }
    }

    float4* __restrict__ o4 =
        (float4*)(out + ((size_t)c * HN + h0 + l) * WD + x0 + wv * 16);
#pragma unroll
    for (int q = 0; q < 4; ++q) {
        float4 v;
        v.x = acc[4*q]; v.y = acc[4*q+1]; v.z = acc[4*q+2]; v.w = acc[4*q+3];
        if (ACC) {
            float4 o = o4[q];
            v.x += o.x; v.y += o.y; v.z += o.z; v.w += o.w;
        }
        o4[q] = v;
    }
}

// ================= conv along H (axis 1), 4-stage LDS =================
// Block: 256 thr = 4 waves. Tile: 64 output rows x 64 cols; lane = col.
// Stage s stages slab rows [32s-64+h0, +96) x 64 cols (24.6 KB, pitch 64,
// lane-consecutive = conflict-free). Same 3-half-buffer inner loop as conv_w.
__global__ __launch_bounds__(256, 5) void conv_h_lds(const float* __restrict__ in,
                                                     const float* __restrict__ kern,
                                                     float* __restrict__ out) {
    __shared__ float lds[96 * 64 + 132];
    float* __restrict__ ldsK = lds + 96 * 64;
    const int tid = threadIdx.x;
    const int x0  = blockIdx.x * 64;
    const int h0  = blockIdx.y * 64;
    const int c   = blockIdx.z;
    const float* __restrict__ in_c = in + (size_t)c * HN * WN + x0;

    if (tid < 132) ldsK[tid] = (tid < KN) ? kern[c * KN + tid] : 0.f;

    const int wv = tid >> 6;            // wave -> output row chunk
    const int l  = tid & 63;            // lane = col
    const int baseRow = wv * 16;        // slab row of window element 0
    const int col = tid & 63;           // staging: lane-coalesced
    const int r4  = tid >> 6;           // 0..3; rows r4 + 4k

    float acc[16];
#pragma unroll
    for (int t = 0; t < 16; ++t) acc[t] = 0.f;

#pragma unroll 1
    for (int s = 0; s < 4; ++s) {
        __syncthreads();                // prior stage reads done
        const int off = h0 + 32 * s - 64;   // global row of slab row 0
        if (off >= 0 && off + 96 <= HN) {   // interior fast path
#pragma unroll
            for (int k = 0; k < 24; ++k)
                lds[(r4 + 4 * k) * 64 + col] =
                    in_c[(size_t)(off + r4 + 4 * k) * WN + col];
        } else {
#pragma unroll
            for (int k = 0; k < 24; ++k) {
                int g  = off + r4 + 4 * k;
                int gc = min(max(g, 0), HN - 1);
                float v = in_c[(size_t)gc * WN + col];
                lds[(r4 + 4 * k) * 64 + col] = (g == gc) ? v : 0.f;
            }
        }
        __syncthreads();

        float H0[16], H1[16], H2[16];
#pragma unroll
        for (int i = 0; i < 16; ++i) H0[i] = lds[(baseRow + i) * 64 + l];
#pragma unroll
        for (int i = 0; i < 16; ++i) H1[i] = lds[(baseRow + 16 + i) * 64 + l];

        const float4* __restrict__ k4 = (const float4*)ldsK;
        float4 kc = k4[8 * s];
#pragma unroll
        for (int q = 0; q < 8; ++q) {       // 4 taps per q, 32 taps/stage
            float4 kn = (q < 7) ? k4[8 * s + q + 1] : kc;
#pragma unroll
            for (int u = 0; u < 4; ++u) {
                const int up = 4 * q + u;
                const float kj = (u == 0) ? kc.x : (u == 1) ? kc.y
                               : (u == 2) ? kc.z : kc.w;
#pragma unroll
                for (int t = 0; t < 16; ++t) {
                    const int e = up + t;
                    const float val = (e < 16) ? H0[e]
                                    : (e < 32) ? H1[e - 16] : H2[e - 32];
                    acc[t] = fmaf(val, kj, acc[t]);
                }
            }
            if (q == 0) {                   // prefetch H2: consumed from q=4
#pragma unroll
                for (int i = 0; i < 16; ++i)
                    H2[i] = lds[(baseRow + 32 + i) * 64 + l];
            }
            kc = kn;
        }
        if (s == 3) {                       // tap 128 uses H2 exactly
            const float k128 = ldsK[128];
#pragma unroll
            for (int t = 0; t < 16; ++t) acc[t] = fmaf(H2[t], k128, acc[t]);
        }
    }

    float* __restrict__ ob = out + ((size_t)c * HN + h0 + wv * 16) * WN + x0 + l;
#pragma unroll
    for (int t = 0; t < 16; ++t) ob[(size_t)t * WN] = acc[t];
}

// ---------------- forward rotate of implicitly-padded C ----------------
// Branchless: clamped in-bounds addresses + zero weights; 4 outputs/thread.
__global__ __launch_bounds__(256) void rot_fwd_k(const float* __restrict__ Cin,
                                                 float* __restrict__ out,
                                                 float ca, float sa) {
    const int jb = blockIdx.x * 128 + threadIdx.x;  // + q*32
    const int i  = blockIdx.y * 8 + threadIdx.y;    // 0..255
    const int c  = blockIdx.z;
    const float cc = (SN - 1) * 0.5f;               // 127.5
    const float yy = (float)i - cc;
    const float* __restrict__ base = Cin + (size_t)c * HN * WN;
    float* __restrict__ orow = out + ((size_t)c * SN + i) * SN;
#pragma unroll
    for (int q = 0; q < 4; ++q) {
        const int j = jb + q * 32;
        float xx = (float)j - cc;
        float sy = ca * yy + sa * xx + cc;
        float sx = -sa * yy + ca * xx + cc;
        float y0f = floorf(sy), x0f = floorf(sx);
        float fy = sy - y0f, fx = sx - x0f;
        int y0 = (int)y0f, x0i = (int)x0f;
        int p  = x0i - PADN;                        // col into C
        int y0c = min(max(y0, 0), HN - 1);
        int y1c = min(max(y0 + 1, 0), HN - 1);
        int p0c = min(max(p, 0), WN - 1);
        int p1c = min(max(p + 1, 0), WN - 1);
        float wy0 = ((unsigned)y0       < (unsigned)HN) ? (1.f - fy) : 0.f;
        float wy1 = ((unsigned)(y0 + 1) < (unsigned)HN) ? fy : 0.f;
        float wx0 = ((unsigned)p        < (unsigned)WN) ? (1.f - fx) : 0.f;
        float wx1 = ((unsigned)(p + 1)  < (unsigned)WN) ? fx : 0.f;
        const float* r0 = base + (size_t)y0c * WN;
        const float* r1 = base + (size_t)y1c * WN;
        float v00 = r0[p0c], v01 = r0[p1c];
        float v10 = r1[p0c], v11 = r1[p1c];
        orow[j] = wy0 * (wx0 * v00 + wx1 * v01) + wy1 * (wx0 * v10 + wx1 * v11);
    }
}

// ---------------- inverse rotate + accumulate into cropped acc -------------
__global__ __launch_bounds__(256) void rot_bwd_k(const float* __restrict__ U,
                                                 float* __restrict__ acc,
                                                 float ca, float sa) {
    const int xb = blockIdx.x * 64 + threadIdx.x;  // + q*32
    const int i  = blockIdx.y * 8 + threadIdx.y;   // 0..255
    const int c  = blockIdx.z;
    const float cc = (SN - 1) * 0.5f;
    const float yy = (float)i - cc;
    const float* __restrict__ base = U + (size_t)c * SN * SN;
    float* __restrict__ arow = acc + ((size_t)c * HN + i) * WN;
#pragma unroll
    for (int q = 0; q < 2; ++q) {
        const int xc = xb + q * 32;
        const int j  = xc + PADN;
        float xx = (float)j - cc;
        float sy = ca * yy + sa * xx + cc;
        float sx = -sa * yy + ca * xx + cc;
        float y0f = floorf(sy), x0f = floorf(sx);
        float fy = sy - y0f, fx = sx - x0f;
        int y0 = (int)y0f, x0i = (int)x0f;
        int y0c = min(max(y0, 0), SN - 1);
        int y1c = min(max(y0 + 1, 0), SN - 1);
        int p0c = min(max(x0i, 0), SN - 1);
        int p1c = min(max(x0i + 1, 0), SN - 1);
        float wy0 = ((unsigned)y0        < (unsigned)SN) ? (1.f - fy) : 0.f;
        float wy1 = ((unsigned)(y0 + 1)  < (unsigned)SN) ? fy : 0.f;
        float wx0 = ((unsigned)x0i       < (unsigned)SN) ? (1.f - fx) : 0.f;
        float wx1 = ((unsigned)(x0i + 1) < (unsigned)SN) ? fx : 0.f;
        const float* r0 = base + (size_t)y0c * SN;
        const float* r1 = base + (size_t)y1c * SN;
        float v00 = r0[p0c], v01 = r0[p1c];
        float v10 = r1[p0c], v11 = r1[p1c];
        arow[xc] += wy0 * (wx0 * v00 + wx1 * v01) + wy1 * (wx0 * v10 + wx1 * v11);
    }
}

// ---------------- finalize: out = (C + acc) / norm[c], float4 ----------------
__global__ __launch_bounds__(256) void final_k(float* __restrict__ outC,
                                               const float* __restrict__ acc,
                                               const float* __restrict__ norm) {
    size_t i4 = (size_t)blockIdx.x * 256 + threadIdx.x;
    int c = (int)(i4 / (HN * WN / 4));
    float4* o4 = (float4*)outC;
    const float4* a4 = (const float4*)acc;
    float inv = 1.f / norm[c];
    float4 o = o4[i4], a = a4[i4];
    o.x = (o.x + a.x) * inv; o.y = (o.y + a.y) * inv;
    o.z = (o.z + a.z) * inv; o.w = (o.w + a.w) * inv;
    o4[i4] = o;
}

extern "C" void kernel_launch(void* const* d_in, const int* in_sizes, int n_in,
                              void* d_out, int out_size, void* d_ws, size_t ws_size,
                              hipStream_t stream) {
    const float* x    = (const float*)d_in[0];
    const float* kg   = (const float*)d_in[1];
    const float* kw   = (const float*)d_in[2];
    const float* kiso = (const float*)d_in[3];
    const float* norm = (const float*)d_in[4];

    float* C = (float*)d_out;                 // 256*256*192 floats
    float* ws = (float*)d_ws;
    const size_t IMG = (size_t)CN * HN * WN;  // 12,582,912
    const size_t PSQ = (size_t)CN * SN * SN;  // 16,777,216
    float* B   = ws;                          // IMG
    float* acc = ws + IMG;                    // IMG
    float* T   = ws + 2 * IMG;                // PSQ
    float* U   = T + PSQ;                     // PSQ

    const dim3 blk256(256);
    const dim3 convHGrid(WN / 64, HN / 64, CN);
    const dim3 convW192Grid(WN / 64, HN / 64, CN);
    const dim3 convW256Grid(SN / 64, HN / 64, CN);
    const dim3 rotFGrid(SN / 128, SN / 8, CN), rotBlk(32, 8);
    const dim3 rotBGrid(WN / 64, SN / 8, CN);

    // 1-2: gaussian separable conv -> C (d_out)
    conv_h_lds<<<convHGrid, blk256, 0, stream>>>(x, kg, B);
    conv_w_lds<WN, false><<<convW192Grid, blk256, 0, stream>>>(B, kg, C);
    // 3-4: iso separable conv -> acc
    conv_h_lds<<<convHGrid, blk256, 0, stream>>>(C, kiso, B);
    conv_w_lds<WN, false><<<convW192Grid, blk256, 0, stream>>>(B, kiso, acc);
    // 5: i=0 tail term (identity rotation): acc += conv_w(C, kw)
    conv_w_lds<WN, true><<<convW192Grid, blk256, 0, stream>>>(C, kw, acc);
    // 6-11: i=1,2 tail terms
    const double a1 = 60.0 * M_PI / 180.0, a2 = 120.0 * M_PI / 180.0;
    const float c1 = (float)cos(a1), s1 = (float)sin(a1);
    const float c2 = (float)cos(a2), s2 = (float)sin(a2);

    rot_fwd_k<<<rotFGrid, rotBlk, 0, stream>>>(C, T, c1, s1);
    conv_w_lds<SN, false><<<convW256Grid, blk256, 0, stream>>>(T, kw, U);
    rot_bwd_k<<<rotBGrid, rotBlk, 0, stream>>>(U, acc, c1, -s1);

    rot_fwd_k<<<rotFGrid, rotBlk, 0, stream>>>(C, T, c2, s2);
    conv_w_lds<SN, false><<<convW256Grid, blk256, 0, stream>>>(T, kw, U);
    rot_bwd_k<<<rotBGrid, rotBlk, 0, stream>>>(U, acc, c2, -s2);

    // 12: out = (C + acc) / norm[c]
    final_k<<<(unsigned)(IMG / 4 / 256), blk256, 0, stream>>>(C, acc, norm);
    (void)in_sizes; (void)n_in; (void)out_size; (void)ws_size;
}